// Round 14
// baseline (245.655 us; speedup 1.0000x reference)
//
#include <hip/hip_runtime.h>
#include <hip/hip_bf16.h>

typedef __attribute__((ext_vector_type(8)))  short bf16x8_t;
typedef __attribute__((ext_vector_type(16))) float f32x16_t;
typedef __attribute__((ext_vector_type(4)))  float f32x4_t;

#define HN 10
#define BN 32768
#define DH 256
#define MT 64

// middle layers: 16 K-steps (bias via acc-init); finals keep 17 (bias MFMA)
#define KS17 17
#define HE    65536              // elems per (arr,head) weight matrix (16 ks)
#define ARRE  655360             // per layer-array

// LDS: bufA 32KB + s5 2KB (4 partials x 64 rows x 2)
#define OFF_A     0
#define OFF_S5    32768
#define SMEM_BYTES 34816

#define MFMA32 __builtin_amdgcn_mfma_f32_32x32x16_bf16

// LDS-only barrier: do NOT drain vmcnt -> in-flight weight loads survive.
#define BAR_LDS() asm volatile("s_waitcnt lgkmcnt(0)\ns_barrier" ::: "memory")

__device__ __forceinline__ unsigned swzoff(int row, int colb) {
  // [64][256] bf16 row-major, 512B/row; XOR row bits into byte bits 4-8
  return (unsigned)(row * 512 + (colb ^ ((row & 31) << 4)));
}

__device__ __forceinline__ unsigned short f2bf(float v) {
  __hip_bfloat16 hb = __float2bfloat16(v);
  return *reinterpret_cast<unsigned short*>(&hb);
}
__device__ __forceinline__ unsigned pk2bf(float lo, float hi_) {
  return (unsigned)f2bf(lo) | ((unsigned)f2bf(hi_) << 16);
}

// ---------------- prep kernels ----------------
struct WPtrs { const float* w[5]; const float* b[5]; };

// [arr][h][ks(16)][nt(8)][lane(64)][8]
extern "C" __global__ void pack_big(WPtrs p, unsigned short* __restrict__ dst)
{
  int g = blockIdx.x * blockDim.x + threadIdx.x;  // 409600
  if (g >= 5 * HN * 16 * 8 * 64) return;
  int lane = g & 63; int t = g >> 6;
  int nt = t & 7; t >>= 3;
  int ks = t & 15; t >>= 4;
  int h = t % HN;
  int a = t / HN;
  int col = nt * 32 + (lane & 31);
  int hi = lane >> 5;
  const float* src = p.w[a] + (size_t)h * 65536 + col * 256 + ks * 16 + hi * 8;
  unsigned short* d = dst + (size_t)a * ARRE + (size_t)h * HE
                    + ((ks * 8 + nt) * 64 + lane) * 8;
  #pragma unroll
  for (int j = 0; j < 8; ++j) d[j] = f2bf(src[j]);
}

// bias table in C^T acc-init order: [arr][h][grp(8)][hi(2)][16]
// value = b[arr][h*256 + grp*32 + 8*(i>>2) + 4*hi + (i&3)]
extern "C" __global__ void pack_bias(WPtrs p, float* __restrict__ dst)
{
  int g = blockIdx.x * blockDim.x + threadIdx.x;  // 12800
  if (g >= 5 * HN * 8 * 2 * 16) return;
  int i  = g & 15; int t = g >> 4;
  int hi = t & 1;  t >>= 1;
  int grp = t & 7; t >>= 3;
  int h = t % HN;
  int a = t / HN;
  int col = grp * 32 + 8 * (i >> 2) + 4 * hi + (i & 3);
  dst[g] = p.b[a][(size_t)h * 256 + col];
}

// [br][h][ks(17)][lane(64)][8] ; ks==16 = bias
extern "C" __global__ void pack_w5(const float* __restrict__ w51, const float* __restrict__ w52,
                                   const float* __restrict__ b51, const float* __restrict__ b52,
                                   unsigned short* __restrict__ dst)
{
  int g = blockIdx.x * blockDim.x + threadIdx.x;  // 21760
  if (g >= 2 * HN * KS17 * 64) return;
  int lane = g & 63; int t = g >> 6;
  int ks = t % KS17; t /= KS17;
  int h = t % HN;
  int br = t / HN;
  const float* w = br ? w52 : w51;   // (10,2,256)
  const float* b = br ? b52 : b51;   // (10,2)
  int col = lane & 31;
  int hi = lane >> 5;
  unsigned short* d = dst + ((size_t)(br * HN + h) * KS17 + ks) * 512 + lane * 8;
  if (ks < 16) {
    int k = ks * 16 + hi * 8;
    #pragma unroll
    for (int j = 0; j < 8; ++j) {
      float v = (col < 2) ? w[(size_t)h * 512 + col * 256 + k + j] : 0.f;
      d[j] = f2bf(v);
    }
  } else {
    float bv = (col < 2) ? b[(size_t)h * 2 + col] : 0.f;
    #pragma unroll
    for (int j = 0; j < 8; ++j) d[j] = (hi == 0 && j == 0) ? f2bf(bv) : (unsigned short)0;
  }
}

// W1 (10,256,4)+b1 -> padded K=16 frags: [h][nt(8)][lane(64)][8]; bias at k=4
extern "C" __global__ void pack_w1(const float* __restrict__ w1, const float* __restrict__ b1,
                                   unsigned short* __restrict__ dst)
{
  int g = blockIdx.x * blockDim.x + threadIdx.x;  // 5120
  if (g >= HN * 8 * 64) return;
  int lane = g & 63; int t = g >> 6;
  int nt = t & 7;
  int h = t >> 3;
  int col = nt * 32 + (lane & 31);
  int hi = lane >> 5;
  unsigned short* d = dst + (size_t)h * 4096 + ((size_t)nt * 64 + lane) * 8;
  #pragma unroll
  for (int j = 0; j < 8; ++j) {
    int k = hi * 8 + j;
    float v = 0.f;
    if (k < 4)       v = w1[(size_t)h * 1024 + col * 4 + k];
    else if (k == 4) v = b1[(size_t)h * 256 + col];
    d[j] = f2bf(v);
  }
}

// ---------------- main kernel ----------------
// 256-thread blocks, 4 waves, 3 blocks/CU. Block = (64 rows, head).
// Single 32KB act buffer; x2 saved bf16-packed in 32 VGPRs across branch 1.
// Wave tile 64x64 (cols = wave*64). C^T in regs: mfma(W, act) -> lane&31 =
// batch row, regs = out cols. Bias enters via acc-init (f32 table).

template<bool SAVE>
__device__ __forceinline__ void write_actT(char* sout, const f32x16_t acc[2][2],
                                           unsigned sv[2][2][8], int lane, int wave)
{
  const int r31 = lane & 31, hi = lane >> 5;
  #pragma unroll
  for (int mt = 0; mt < 2; ++mt) {
    const int row = mt * 32 + r31;
    #pragma unroll
    for (int nt = 0; nt < 2; ++nt) {
      #pragma unroll
      for (int g = 0; g < 4; ++g) {
        const int col0 = (wave * 2 + nt) * 32 + 8 * g + 4 * hi;
        unsigned w0 = pk2bf(fmaxf(acc[mt][nt][4 * g + 0], 0.f),
                            fmaxf(acc[mt][nt][4 * g + 1], 0.f));
        unsigned w1 = pk2bf(fmaxf(acc[mt][nt][4 * g + 2], 0.f),
                            fmaxf(acc[mt][nt][4 * g + 3], 0.f));
        if (SAVE) { sv[mt][nt][2 * g] = w0; sv[mt][nt][2 * g + 1] = w1; }
        unsigned long long pk = (unsigned long long)w0 | ((unsigned long long)w1 << 32);
        *(unsigned long long*)(sout + swzoff(row, col0 * 2)) = pk;
      }
    }
  }
}

// K-loop only: 64x256 @ 256x256 + bias(acc-init), results left in acc (C^T).
__device__ __forceinline__ void gemm_acc(const char* buf, const char* wb,
                                         const float* __restrict__ bt,
                                         f32x16_t acc[2][2],
                                         int lane, int wave)
{
  const int r31 = lane & 31, hi = lane >> 5;
  // bias init: f32 table pre-arranged in C^T register order
  #pragma unroll
  for (int nt = 0; nt < 2; ++nt) {
    const float* bp = bt + (size_t)(wave * 2 + nt) * 32 + hi * 16;
    #pragma unroll
    for (int q = 0; q < 4; ++q) {
      f32x4_t v = *(const f32x4_t*)(bp + q * 4);
      #pragma unroll
      for (int j = 0; j < 4; ++j) {
        acc[0][nt][q * 4 + j] = v[j];
        acc[1][nt][q * 4 + j] = v[j];
      }
    }
  }

  bf16x8_t c0[2], c1[2], c2[2];
  #pragma unroll
  for (int nt = 0; nt < 2; ++nt) {
    c0[nt] = *(const bf16x8_t*)(wb + nt * 1024);
    c1[nt] = *(const bf16x8_t*)(wb + 8192 + nt * 1024);
  }
  #pragma unroll
  for (int ks = 0; ks < 16; ++ks) {
    if (ks < 14) {
      #pragma unroll
      for (int nt = 0; nt < 2; ++nt)
        c2[nt] = *(const bf16x8_t*)(wb + (ks + 2) * 8192 + nt * 1024);
    }
    bf16x8_t a[2];
    #pragma unroll
    for (int mt = 0; mt < 2; ++mt)
      a[mt] = *(const bf16x8_t*)(buf + swzoff(mt * 32 + r31, ks * 32 + hi * 16));
    #pragma unroll
    for (int mt = 0; mt < 2; ++mt) {
      acc[mt][0] = MFMA32(c0[0], a[mt], acc[mt][0], 0, 0, 0);
      acc[mt][1] = MFMA32(c0[1], a[mt], acc[mt][1], 0, 0, 0);
    }
    #pragma unroll
    for (int nt = 0; nt < 2; ++nt) { c0[nt] = c1[nt]; c1[nt] = c2[nt]; }
  }
}

// Fused final: relu(acc) -> bf16 A-frags in-register (2x permlane32_swap per
// k-step) -> 8 MFMA vs w5pk frags (wave w covers k in [64w, 64w+64); wave 0
// adds the ones x bias step) -> 4-partial reduce via s5 -> raw f32 to ws.
// RESTORE: concurrently write saved x2 (sv) back into bufA.
template<bool RESTORE>
__device__ __forceinline__ void fused_final(f32x16_t acc[2][2], unsigned sv[2][2][8],
                                            const unsigned short* __restrict__ w5,
                                            float* s5, float* __restrict__ wsout,
                                            char* bufA, int row0, int tid,
                                            int lane, int wave, bf16x8_t ones)
{
  const int r31 = lane & 31, hi = lane >> 5;
  bf16x8_t bf[4];
  #pragma unroll
  for (int s = 0; s < 4; ++s)
    bf[s] = *(const bf16x8_t*)(w5 + (size_t)((wave * 4 + s) * 64 + lane) * 8);
  bf16x8_t bbias;
  if (wave == 0) bbias = *(const bf16x8_t*)(w5 + (size_t)(16 * 64 + lane) * 8);

  f32x16_t p[2];
  #pragma unroll
  for (int i = 0; i < 16; ++i) { p[0][i] = 0.f; p[1][i] = 0.f; }

  #pragma unroll
  for (int mt = 0; mt < 2; ++mt) {
    #pragma unroll
    for (int nt = 0; nt < 2; ++nt) {
      #pragma unroll
      for (int sh = 0; sh < 2; ++sh) {
        unsigned w0 = pk2bf(fmaxf(acc[mt][nt][8 * sh + 0], 0.f),
                            fmaxf(acc[mt][nt][8 * sh + 1], 0.f));
        unsigned w1 = pk2bf(fmaxf(acc[mt][nt][8 * sh + 2], 0.f),
                            fmaxf(acc[mt][nt][8 * sh + 3], 0.f));
        unsigned v0 = pk2bf(fmaxf(acc[mt][nt][8 * sh + 4], 0.f),
                            fmaxf(acc[mt][nt][8 * sh + 5], 0.f));
        unsigned v1 = pk2bf(fmaxf(acc[mt][nt][8 * sh + 6], 0.f),
                            fmaxf(acc[mt][nt][8 * sh + 7], 0.f));
        asm("v_permlane32_swap_b32 %0, %1" : "+v"(w0), "+v"(v0));
        asm("v_permlane32_swap_b32 %0, %1" : "+v"(w1), "+v"(v1));
        union { unsigned u[4]; bf16x8_t f; } afu;
        afu.u[0] = w0; afu.u[1] = w1; afu.u[2] = v0; afu.u[3] = v1;
        p[mt] = MFMA32(afu.f, bf[nt * 2 + sh], p[mt], 0, 0, 0);
      }
    }
  }
  if (wave == 0) {
    p[0] = MFMA32(ones, bbias, p[0], 0, 0, 0);
    p[1] = MFMA32(ones, bbias, p[1], 0, 0, 0);
  }

  if (RESTORE) {
    #pragma unroll
    for (int mt = 0; mt < 2; ++mt) {
      const int row = mt * 32 + r31;
      #pragma unroll
      for (int nt = 0; nt < 2; ++nt) {
        #pragma unroll
        for (int g = 0; g < 4; ++g) {
          const int col0 = (wave * 2 + nt) * 32 + 8 * g + 4 * hi;
          unsigned long long pk = (unsigned long long)sv[mt][nt][2 * g]
                                | ((unsigned long long)sv[mt][nt][2 * g + 1] << 32);
          *(unsigned long long*)(bufA + swzoff(row, col0 * 2)) = pk;
        }
      }
    }
  }

  if (r31 < 2) {
    #pragma unroll
    for (int mt = 0; mt < 2; ++mt)
      #pragma unroll
      for (int r = 0; r < 16; ++r) {
        int row = mt * 32 + (r & 3) + 8 * (r >> 2) + 4 * hi;
        s5[wave * 128 + row * 2 + r31] = p[mt][r];
      }
  }
  BAR_LDS();
  if (tid < 128) {
    float sum = s5[tid] + s5[128 + tid] + s5[256 + tid] + s5[384 + tid];
    wsout[(size_t)(row0 + (tid >> 1)) * 2 + (tid & 1)] = sum;
  }
}

extern "C" __global__ __launch_bounds__(256, 3)
void abnet_main(const float* __restrict__ x,
                const unsigned short* __restrict__ wpk,
                const unsigned short* __restrict__ w5pk,
                const unsigned short* __restrict__ w1pk,
                const float* __restrict__ btab,
                float* __restrict__ ws51, float* __restrict__ ws52)
{
  extern __shared__ char smem[];
  char*  bufA = smem + OFF_A;
  float* s5   = (float*)(smem + OFF_S5);

  const int tid  = threadIdx.x;
  const int lane = tid & 63, wave = tid >> 6;
  // XCD-chunked swizzle: 640 consecutive logical blocks per XCD (5120 % 8 == 0)
  const int L  = (blockIdx.x & 7) * 640 + (blockIdx.x >> 3);
  const int rt = L & 511;
  const int h  = L >> 9;                 // 0..9
  const int row0 = rt * MT;

  const int r31 = lane & 31, hi = lane >> 5;

  // ones-frag: B[k][*]=1 at k-slot 0 of hi=0 (finals' bias step; L1's k=4)
  bf16x8_t ones;
  #pragma unroll
  for (int j = 0; j < 8; ++j) ones[j] = 0;
  if (hi == 0) ones[0] = (short)0x3F80;   // bf16 1.0

  // per-wave weight bases (frag (ks, c=wave*2+nt) at byte ((ks*8+c)*64+lane)*16)
  const size_t woff = (size_t)(wave * 2) * 1024 + (size_t)lane * 16;
  const char* W2w  = (const char*)(wpk + (size_t)h * HE) + woff;
  const char* W31w = (const char*)(wpk + 1 * (size_t)ARRE + (size_t)h * HE) + woff;
  const char* W32w = (const char*)(wpk + 2 * (size_t)ARRE + (size_t)h * HE) + woff;
  const char* W41w = (const char*)(wpk + 3 * (size_t)ARRE + (size_t)h * HE) + woff;
  const char* W42w = (const char*)(wpk + 4 * (size_t)ARRE + (size_t)h * HE) + woff;
  // bias tables: [arr][h] blocks of 8*2*16 = 256 floats
  const float* bt2  = btab + (size_t)(0 * HN + h) * 256;
  const float* bt31 = btab + (size_t)(1 * HN + h) * 256;
  const float* bt32 = btab + (size_t)(2 * HN + h) * 256;
  const float* bt41 = btab + (size_t)(3 * HN + h) * 256;
  const float* bt42 = btab + (size_t)(4 * HN + h) * 256;

  unsigned sv[2][2][8];   // x2 tile, bf16-packed (32 VGPR)
  f32x16_t acc[2][2];

  // ---- layer 1 via padded-K MFMA (K=4 + bias at k=4), C^T -> bufA ----
  {
    const char* w1b = (const char*)(w1pk + (size_t)h * 4096) + woff;
    bf16x8_t wf[2];
    #pragma unroll
    for (int nt = 0; nt < 2; ++nt) wf[nt] = *(const bf16x8_t*)(w1b + nt * 1024);
    #pragma unroll
    for (int mt = 0; mt < 2; ++mt)
      #pragma unroll
      for (int nt = 0; nt < 2; ++nt)
        #pragma unroll
        for (int i = 0; i < 16; ++i) acc[mt][nt][i] = 0.f;
    #pragma unroll
    for (int mt = 0; mt < 2; ++mt) {
      int row = row0 + mt * 32 + r31;
      f32x4_t xv = *(const f32x4_t*)(x + (size_t)row * 4);
      bf16x8_t af;
      #pragma unroll
      for (int j = 0; j < 8; ++j) {
        short v = 0;
        if (hi == 0) {
          if (j < 4)       v = (short)f2bf(xv[j]);
          else if (j == 4) v = (short)0x3F80;   // ones slot for bias row
        }
        af[j] = v;
      }
      acc[mt][0] = MFMA32(wf[0], af, acc[mt][0], 0, 0, 0);
      acc[mt][1] = MFMA32(wf[1], af, acc[mt][1], 0, 0, 0);
    }
    write_actT<false>(bufA, acc, sv, lane, wave);
    BAR_LDS();
  }

  // ---- shared trunk: x2 in place, saved to regs ----
  gemm_acc(bufA, W2w, bt2, acc, lane, wave);
  BAR_LDS();
  write_actT<true>(bufA, acc, sv, lane, wave);
  BAR_LDS();

  // ---- branch 1: x31 (in place), then x41 + f51 fused (+ restore x2) ----
  gemm_acc(bufA, W31w, bt31, acc, lane, wave);
  BAR_LDS();
  write_actT<false>(bufA, acc, sv, lane, wave);
  BAR_LDS();

  gemm_acc(bufA, W41w, bt41, acc, lane, wave);
  BAR_LDS();   // all x31 reads done -> restore may overwrite bufA
  fused_final<true>(acc, sv, w5pk + (size_t)h * (KS17 * 512), s5,
                    ws51 + (size_t)h * BN * 2, bufA, row0, tid, lane, wave, ones);

  // ---- branch 2: x32 (in place, bufA = x2), then x42 + f52 fused ----
  gemm_acc(bufA, W32w, bt32, acc, lane, wave);
  BAR_LDS();
  write_actT<false>(bufA, acc, sv, lane, wave);
  BAR_LDS();

  gemm_acc(bufA, W42w, bt42, acc, lane, wave);
  fused_final<false>(acc, sv, w5pk + (size_t)(HN + h) * (KS17 * 512), s5,
                     ws52 + (size_t)h * BN * 2, bufA, row0, tid, lane, wave, ones);
}

// ---------------- epilogue: CBF + softmax-weighted head combine ----------------
extern "C" __global__ __launch_bounds__(256)
void abnet_epi(const float* __restrict__ x, const float* __restrict__ wt,
               const float* __restrict__ mean, const float* __restrict__ stdv,
               const float* __restrict__ mlab, const float* __restrict__ slab,
               const float* __restrict__ ws51, const float* __restrict__ ws52,
               float* __restrict__ out)
{
  const int row = blockIdx.x * 256 + threadIdx.x;
  f32x4_t xr = *(const f32x4_t*)(x + (size_t)row * 4);
  float t1  = xr[0] * stdv[0] + mean[0];
  float w1v = xr[1] * stdv[1] + mean[1];
  float t2  = xr[2] * stdv[2] + mean[2];
  float w2v = xr[3] * stdv[3] + mean[3];
  float s1, c1, s2, c2;
  sincosf(t1, &s1, &c1);
  sincosf(t2, &s2, &c2);
  float px = 3.f * c1 + 3.f * c2;                // OBS_X = 0
  float py = 3.f * s1 + 3.f * s2 - 7.f;          // OBS_Y = 7
  float vx = -3.f * s1 * w1v - 3.f * s2 * w2v;
  float vy =  3.f * c1 * w1v + 3.f * c2 * w2v;
  float e_bar  = px * px + py * py - 16.f;       // R^2
  float e_bdot = 2.f * (px * vx + py * vy);
  float e_lf2b = 2.f * vx * vx + 2.f * vy * vy
               + 2.f * px * (-3.f * c1 * w1v * w1v - 3.f * c2 * w2v * w2v)
               + 2.f * py * (-3.f * s1 * w1v * w1v - 3.f * s2 * w2v * w2v);
  float e_g1 = 6.f * (px * s1 - py * c1);
  float e_g2 = 6.f * (px * s2 - py * c2);
  float e_ggi = 1.f / (e_g1 * e_g1 + e_g2 * e_g2);

  float m = wt[0];
  for (int i = 1; i < HN; ++i) m = fmaxf(m, wt[i]);
  float s = 0.f;
  for (int i = 0; i < HN; ++i) s += __expf(wt[i] - m);
  float sm_inv = 1.f / s;
  float ml0 = mlab[0], ml1 = mlab[1];
  float isl0 = 1.f / slab[0], isl1 = 1.f / slab[1];

  float a0r = 4.f / (1.f + __expf(-ws52[(size_t)row * 2 + 0]));   // head 0, col 0
  float accu0 = 0.f, accu1 = 0.f;
  for (int h = 0; h < HN; ++h) {
    float u1 = -ws51[((size_t)h * BN + row) * 2 + 0];
    float u2 = -ws51[((size_t)h * BN + row) * 2 + 1];
    float bi = 4.f / (1.f + __expf(-ws52[((size_t)h * BN + row) * 2 + 1]));
    float hv   = e_lf2b + (a0r + bi) * e_bdot + a0r * bi * e_bar;
    float viol = u1 * e_g1 + u2 * e_g2 - hv;
    float lam  = fmaxf(viol, 0.f) * e_ggi;
    float uu1 = u1 - lam * e_g1;
    float uu2 = u2 - lam * e_g2;
    float whv = __expf(wt[h] - m) * sm_inv;
    accu0 += whv * (uu1 - ml0) * isl0;
    accu1 += whv * (uu2 - ml1) * isl1;
  }
  float2 o; o.x = accu0; o.y = accu1;
  *(float2*)(out + (size_t)row * 2) = o;
}

// ---------------- launch ----------------
extern "C" void kernel_launch(void* const* d_in, const int* in_sizes, int n_in,
                              void* d_out, int out_size, void* d_ws, size_t ws_size,
                              hipStream_t stream)
{
  const float* x    = (const float*)d_in[0];
  const float* wt   = (const float*)d_in[2];
  const float* mean = (const float*)d_in[3];
  const float* stdv = (const float*)d_in[4];
  const float* mlab = (const float*)d_in[5];
  const float* slab = (const float*)d_in[6];
  const float* W1   = (const float*)d_in[7];
  const float* b1   = (const float*)d_in[8];
  WPtrs wp;
  wp.w[0] = (const float*)d_in[9];   // W2
  wp.w[1] = (const float*)d_in[11];  // W31
  wp.w[2] = (const float*)d_in[13];  // W32
  wp.w[3] = (const float*)d_in[15];  // W41
  wp.w[4] = (const float*)d_in[17];  // W42
  wp.b[0] = (const float*)d_in[10];  // b2
  wp.b[1] = (const float*)d_in[12];  // b31
  wp.b[2] = (const float*)d_in[14];  // b32
  wp.b[3] = (const float*)d_in[16];  // b41
  wp.b[4] = (const float*)d_in[18];  // b42
  const float* W51 = (const float*)d_in[19];
  const float* b51 = (const float*)d_in[20];
  const float* W52 = (const float*)d_in[21];
  const float* b52 = (const float*)d_in[22];

  char* wsb = (char*)d_ws;
  unsigned short* wpk  = (unsigned short*)wsb;                       // 6,553,600 B
  unsigned short* w5pk = (unsigned short*)(wsb + 6553600);           //   348,160 B
  unsigned short* w1pk = (unsigned short*)(wsb + 6901760);           //    81,920 B
  float* btab = (float*)(wsb + 6983680);                             //    51,200 B
  float* ws51 = (float*)(wsb + 7034880);                             // 2,621,440 B
  float* ws52 = (float*)(wsb + 9656320);                             // 2,621,440 B

  hipLaunchKernelGGL(pack_big,  dim3(1600), dim3(256), 0, stream, wp, wpk);
  hipLaunchKernelGGL(pack_bias, dim3(50),   dim3(256), 0, stream, wp, btab);
  hipLaunchKernelGGL(pack_w5,   dim3(85),   dim3(256), 0, stream, W51, W52, b51, b52, w5pk);
  hipLaunchKernelGGL(pack_w1,   dim3(20),   dim3(256), 0, stream, W1, b1, w1pk);

  (void)hipFuncSetAttribute(reinterpret_cast<const void*>(abnet_main),
                            hipFuncAttributeMaxDynamicSharedMemorySize, SMEM_BYTES);
  hipLaunchKernelGGL(abnet_main, dim3(512 * HN), dim3(256), SMEM_BYTES, stream,
                     x, wpk, w5pk, w1pk, btab, ws51, ws52);
  hipLaunchKernelGGL(abnet_epi, dim3(BN / 256), dim3(256), 0, stream,
                     x, wt, mean, stdv, mlab, slab, ws51, ws52, (float*)d_out);
}

// Round 16
// 241.569 us; speedup vs baseline: 1.0169x; 1.0169x over previous
//
#include <hip/hip_runtime.h>
#include <hip/hip_bf16.h>

typedef __attribute__((ext_vector_type(8)))  short bf16x8_t;
typedef __attribute__((ext_vector_type(16))) float f32x16_t;
typedef __attribute__((ext_vector_type(4)))  float f32x4_t;

#define HN 10
#define BN 32768
#define DH 256
#define MT 64

// 17 K-steps per layer (17th = bias row, consumed against a ones-frag)
#define KS17 17
#define HE17   (KS17*8*64*8)     // 69632 elems per (arr,head)
#define ARRE17 (HN*HE17)         // 696320

// LDS: bufA 32KB + s5 2KB (4 partials x 64 rows x 2)
#define OFF_A     0
#define OFF_S5    32768
#define SMEM_BYTES 34816

#define MFMA32 __builtin_amdgcn_mfma_f32_32x32x16_bf16

// LDS-only barrier: do NOT drain vmcnt -> in-flight weight loads survive.
#define BAR_LDS() asm volatile("s_waitcnt lgkmcnt(0)\ns_barrier" ::: "memory")

__device__ __forceinline__ unsigned swzoff(int row, int colb) {
  // [64][256] bf16 row-major, 512B/row; XOR row bits into byte bits 4-8
  return (unsigned)(row * 512 + (colb ^ ((row & 31) << 4)));
}

__device__ __forceinline__ unsigned short f2bf(float v) {
  __hip_bfloat16 hb = __float2bfloat16(v);
  return *reinterpret_cast<unsigned short*>(&hb);
}
__device__ __forceinline__ unsigned pk2bf(float lo, float hi_) {
  return (unsigned)f2bf(lo) | ((unsigned)f2bf(hi_) << 16);
}

// ---------------- prep kernels (layouts verified R1-R13) ----------------
struct WPtrs { const float* w[5]; const float* b[5]; };

// [arr][h][ks(17)][nt(8)][lane(64)][8] ; ks==16 carries the bias row
extern "C" __global__ void pack_big(WPtrs p, unsigned short* __restrict__ dst)
{
  int g = blockIdx.x * blockDim.x + threadIdx.x;  // 435200
  if (g >= 5 * HN * KS17 * 8 * 64) return;
  int lane = g & 63; int t = g >> 6;
  int nt = t & 7; t >>= 3;
  int ks = t % KS17; t /= KS17;
  int h = t % HN;
  int a = t / HN;
  int col = nt * 32 + (lane & 31);
  int hi = lane >> 5;
  unsigned short* d = dst + (size_t)a * ARRE17 + (size_t)h * HE17
                    + ((ks * 8 + nt) * 64 + lane) * 8;
  if (ks < 16) {
    const float* src = p.w[a] + (size_t)h * 65536 + col * 256 + ks * 16 + hi * 8;
    #pragma unroll
    for (int j = 0; j < 8; ++j) d[j] = f2bf(src[j]);
  } else {
    float bv = p.b[a][(size_t)h * 256 + col];
    #pragma unroll
    for (int j = 0; j < 8; ++j) d[j] = (hi == 0 && j == 0) ? f2bf(bv) : (unsigned short)0;
  }
}

// [br][h][ks(17)][lane(64)][8] ; ks==16 = bias
extern "C" __global__ void pack_w5(const float* __restrict__ w51, const float* __restrict__ w52,
                                   const float* __restrict__ b51, const float* __restrict__ b52,
                                   unsigned short* __restrict__ dst)
{
  int g = blockIdx.x * blockDim.x + threadIdx.x;  // 21760
  if (g >= 2 * HN * KS17 * 64) return;
  int lane = g & 63; int t = g >> 6;
  int ks = t % KS17; t /= KS17;
  int h = t % HN;
  int br = t / HN;
  const float* w = br ? w52 : w51;   // (10,2,256)
  const float* b = br ? b52 : b51;   // (10,2)
  int col = lane & 31;
  int hi = lane >> 5;
  unsigned short* d = dst + ((size_t)(br * HN + h) * KS17 + ks) * 512 + lane * 8;
  if (ks < 16) {
    int k = ks * 16 + hi * 8;
    #pragma unroll
    for (int j = 0; j < 8; ++j) {
      float v = (col < 2) ? w[(size_t)h * 512 + col * 256 + k + j] : 0.f;
      d[j] = f2bf(v);
    }
  } else {
    float bv = (col < 2) ? b[(size_t)h * 2 + col] : 0.f;
    #pragma unroll
    for (int j = 0; j < 8; ++j) d[j] = (hi == 0 && j == 0) ? f2bf(bv) : (unsigned short)0;
  }
}

// W1 (10,256,4)+b1 -> padded K=16 frags: [h][nt(8)][lane(64)][8]; bias at k=4
extern "C" __global__ void pack_w1(const float* __restrict__ w1, const float* __restrict__ b1,
                                   unsigned short* __restrict__ dst)
{
  int g = blockIdx.x * blockDim.x + threadIdx.x;  // 5120
  if (g >= HN * 8 * 64) return;
  int lane = g & 63; int t = g >> 6;
  int nt = t & 7;
  int h = t >> 3;
  int col = nt * 32 + (lane & 31);
  int hi = lane >> 5;
  unsigned short* d = dst + (size_t)h * 4096 + ((size_t)nt * 64 + lane) * 8;
  #pragma unroll
  for (int j = 0; j < 8; ++j) {
    int k = hi * 8 + j;
    float v = 0.f;
    if (k < 4)       v = w1[(size_t)h * 1024 + col * 4 + k];
    else if (k == 4) v = b1[(size_t)h * 256 + col];
    d[j] = f2bf(v);
  }
}

// ---------------- main kernel ----------------
// 256-thread blocks, 4 waves, 3 blocks/CU. Block = (64 rows, head).
// Single 32KB act buffer; x2 saved bf16-packed in 32 VGPRs across branch 1.
// Wave tile 64x64 (cols = wave*64). C^T in regs: mfma(W, act) -> lane&31 =
// batch row, regs = out cols. Finals computed FROM REGISTERS (permlane
// A-frag assembly), no LDS round trip for x41/x42.

template<bool SAVE>
__device__ __forceinline__ void write_actT(char* sout, const f32x16_t acc[2][2],
                                           unsigned sv[2][2][8], int lane, int wave)
{
  const int r31 = lane & 31, hi = lane >> 5;
  #pragma unroll
  for (int mt = 0; mt < 2; ++mt) {
    const int row = mt * 32 + r31;
    #pragma unroll
    for (int nt = 0; nt < 2; ++nt) {
      #pragma unroll
      for (int g = 0; g < 4; ++g) {
        const int col0 = (wave * 2 + nt) * 32 + 8 * g + 4 * hi;
        unsigned w0 = pk2bf(fmaxf(acc[mt][nt][4 * g + 0], 0.f),
                            fmaxf(acc[mt][nt][4 * g + 1], 0.f));
        unsigned w1 = pk2bf(fmaxf(acc[mt][nt][4 * g + 2], 0.f),
                            fmaxf(acc[mt][nt][4 * g + 3], 0.f));
        if (SAVE) { sv[mt][nt][2 * g] = w0; sv[mt][nt][2 * g + 1] = w1; }
        unsigned long long pk = (unsigned long long)w0 | ((unsigned long long)w1 << 32);
        *(unsigned long long*)(sout + swzoff(row, col0 * 2)) = pk;
      }
    }
  }
}

// K-loop only: 64x256 @ 256x(256+bias), results left in acc (C^T).
__device__ __forceinline__ void gemm_acc(const char* buf, const char* wb,
                                         f32x16_t acc[2][2],
                                         int lane, int wave, bf16x8_t ones)
{
  const int r31 = lane & 31, hi = lane >> 5;
  #pragma unroll
  for (int mt = 0; mt < 2; ++mt)
    #pragma unroll
    for (int nt = 0; nt < 2; ++nt)
      #pragma unroll
      for (int i = 0; i < 16; ++i) acc[mt][nt][i] = 0.f;

  bf16x8_t c0[2], c1[2], c2[2];
  #pragma unroll
  for (int nt = 0; nt < 2; ++nt) {
    c0[nt] = *(const bf16x8_t*)(wb + nt * 1024);
    c1[nt] = *(const bf16x8_t*)(wb + 8192 + nt * 1024);
  }
  #pragma unroll
  for (int ks = 0; ks < KS17; ++ks) {
    if (ks < KS17 - 2) {
      #pragma unroll
      for (int nt = 0; nt < 2; ++nt)
        c2[nt] = *(const bf16x8_t*)(wb + (ks + 2) * 8192 + nt * 1024);
    }
    bf16x8_t a[2];
    #pragma unroll
    for (int mt = 0; mt < 2; ++mt)
      a[mt] = (ks < 16)
        ? *(const bf16x8_t*)(buf + swzoff(mt * 32 + r31, ks * 32 + hi * 16))
        : ones;
    #pragma unroll
    for (int mt = 0; mt < 2; ++mt) {
      acc[mt][0] = MFMA32(c0[0], a[mt], acc[mt][0], 0, 0, 0);
      acc[mt][1] = MFMA32(c0[1], a[mt], acc[mt][1], 0, 0, 0);
    }
    #pragma unroll
    for (int nt = 0; nt < 2; ++nt) { c0[nt] = c1[nt]; c1[nt] = c2[nt]; }
  }
}

// Fused final: relu(acc) -> bf16 A-frags in-register (2x permlane32_swap per
// k-step) -> 8 MFMA vs w5pk frags (wave w covers k in [64w, 64w+64); wave 0
// adds the ones x bias step) -> 4-partial reduce via s5 -> raw f32 to ws.
// RESTORE: concurrently write saved x2 (sv) back into bufA.
template<bool RESTORE>
__device__ __forceinline__ void fused_final(f32x16_t acc[2][2], unsigned sv[2][2][8],
                                            const unsigned short* __restrict__ w5,
                                            float* s5, float* __restrict__ wsout,
                                            char* bufA, int row0, int tid,
                                            int lane, int wave, bf16x8_t ones)
{
  const int r31 = lane & 31, hi = lane >> 5;
  bf16x8_t bf[4];
  #pragma unroll
  for (int s = 0; s < 4; ++s)
    bf[s] = *(const bf16x8_t*)(w5 + (size_t)((wave * 4 + s) * 64 + lane) * 8);
  bf16x8_t bbias;
  if (wave == 0) bbias = *(const bf16x8_t*)(w5 + (size_t)(16 * 64 + lane) * 8);

  f32x16_t p[2];
  #pragma unroll
  for (int i = 0; i < 16; ++i) { p[0][i] = 0.f; p[1][i] = 0.f; }

  #pragma unroll
  for (int mt = 0; mt < 2; ++mt) {
    #pragma unroll
    for (int nt = 0; nt < 2; ++nt) {
      #pragma unroll
      for (int sh = 0; sh < 2; ++sh) {
        unsigned w0 = pk2bf(fmaxf(acc[mt][nt][8 * sh + 0], 0.f),
                            fmaxf(acc[mt][nt][8 * sh + 1], 0.f));
        unsigned w1 = pk2bf(fmaxf(acc[mt][nt][8 * sh + 2], 0.f),
                            fmaxf(acc[mt][nt][8 * sh + 3], 0.f));
        unsigned v0 = pk2bf(fmaxf(acc[mt][nt][8 * sh + 4], 0.f),
                            fmaxf(acc[mt][nt][8 * sh + 5], 0.f));
        unsigned v1 = pk2bf(fmaxf(acc[mt][nt][8 * sh + 6], 0.f),
                            fmaxf(acc[mt][nt][8 * sh + 7], 0.f));
        asm("v_permlane32_swap_b32 %0, %1" : "+v"(w0), "+v"(v0));
        asm("v_permlane32_swap_b32 %0, %1" : "+v"(w1), "+v"(v1));
        union { unsigned u[4]; bf16x8_t f; } afu;
        afu.u[0] = w0; afu.u[1] = w1; afu.u[2] = v0; afu.u[3] = v1;
        p[mt] = MFMA32(afu.f, bf[nt * 2 + sh], p[mt], 0, 0, 0);
      }
    }
  }
  if (wave == 0) {
    p[0] = MFMA32(ones, bbias, p[0], 0, 0, 0);
    p[1] = MFMA32(ones, bbias, p[1], 0, 0, 0);
  }

  if (RESTORE) {
    #pragma unroll
    for (int mt = 0; mt < 2; ++mt) {
      const int row = mt * 32 + r31;
      #pragma unroll
      for (int nt = 0; nt < 2; ++nt) {
        #pragma unroll
        for (int g = 0; g < 4; ++g) {
          const int col0 = (wave * 2 + nt) * 32 + 8 * g + 4 * hi;
          unsigned long long pk = (unsigned long long)sv[mt][nt][2 * g]
                                | ((unsigned long long)sv[mt][nt][2 * g + 1] << 32);
          *(unsigned long long*)(bufA + swzoff(row, col0 * 2)) = pk;
        }
      }
    }
  }

  // partials: C/D layout col=lane&31 (cols 0,1 valid), row=(r&3)+8(r>>2)+4hi
  if (r31 < 2) {
    #pragma unroll
    for (int mt = 0; mt < 2; ++mt)
      #pragma unroll
      for (int r = 0; r < 16; ++r) {
        int row = mt * 32 + (r & 3) + 8 * (r >> 2) + 4 * hi;
        s5[wave * 128 + row * 2 + r31] = p[mt][r];
      }
  }
  BAR_LDS();
  if (tid < 128) {
    float sum = s5[tid] + s5[128 + tid] + s5[256 + tid] + s5[384 + tid];
    wsout[(size_t)(row0 + (tid >> 1)) * 2 + (tid & 1)] = sum;
  }
}

extern "C" __global__ __launch_bounds__(256, 3)
void abnet_main(const float* __restrict__ x,
                const unsigned short* __restrict__ wpk,
                const unsigned short* __restrict__ w5pk,
                const unsigned short* __restrict__ w1pk,
                float* __restrict__ ws51, float* __restrict__ ws52)
{
  extern __shared__ char smem[];
  char*  bufA = smem + OFF_A;
  float* s5   = (float*)(smem + OFF_S5);

  const int tid  = threadIdx.x;
  const int lane = tid & 63, wave = tid >> 6;
  // XCD-chunked swizzle: 640 consecutive logical blocks per XCD (5120 % 8 == 0)
  const int L  = (blockIdx.x & 7) * 640 + (blockIdx.x >> 3);
  const int rt = L & 511;
  const int h  = L >> 9;                 // 0..9
  const int row0 = rt * MT;

  const int r31 = lane & 31, hi = lane >> 5;

  // ones-frag: B[k][*]=1 at k-slot 0 of hi=0 (k=256 for 17th step; k=4 for L1)
  bf16x8_t ones;
  #pragma unroll
  for (int j = 0; j < 8; ++j) ones[j] = 0;
  if (hi == 0) ones[0] = (short)0x3F80;   // bf16 1.0

  // per-wave weight bases (frag (ks, c=wave*2+nt) at byte ((ks*8+c)*64+lane)*16)
  const size_t woff = (size_t)(wave * 2) * 1024 + (size_t)lane * 16;
  const char* W2w  = (const char*)(wpk + (size_t)h * HE17) + woff;
  const char* W31w = (const char*)(wpk + 1 * (size_t)ARRE17 + (size_t)h * HE17) + woff;
  const char* W32w = (const char*)(wpk + 2 * (size_t)ARRE17 + (size_t)h * HE17) + woff;
  const char* W41w = (const char*)(wpk + 3 * (size_t)ARRE17 + (size_t)h * HE17) + woff;
  const char* W42w = (const char*)(wpk + 4 * (size_t)ARRE17 + (size_t)h * HE17) + woff;

  unsigned sv[2][2][8];   // x2 tile, bf16-packed (32 VGPR)
  f32x16_t acc[2][2];

  // ---- layer 1 via padded-K MFMA (K=4 + bias at k=4), C^T -> bufA ----
  {
    const char* w1b = (const char*)(w1pk + (size_t)h * 4096) + woff;
    bf16x8_t wf[2];
    #pragma unroll
    for (int nt = 0; nt < 2; ++nt) wf[nt] = *(const bf16x8_t*)(w1b + nt * 1024);
    #pragma unroll
    for (int mt = 0; mt < 2; ++mt)
      #pragma unroll
      for (int nt = 0; nt < 2; ++nt)
        #pragma unroll
        for (int i = 0; i < 16; ++i) acc[mt][nt][i] = 0.f;
    #pragma unroll
    for (int mt = 0; mt < 2; ++mt) {
      int row = row0 + mt * 32 + r31;
      f32x4_t xv = *(const f32x4_t*)(x + (size_t)row * 4);
      bf16x8_t af;
      #pragma unroll
      for (int j = 0; j < 8; ++j) {
        short v = 0;
        if (hi == 0) {
          if (j < 4)       v = (short)f2bf(xv[j]);
          else if (j == 4) v = (short)0x3F80;   // ones slot for bias row
        }
        af[j] = v;
      }
      acc[mt][0] = MFMA32(wf[0], af, acc[mt][0], 0, 0, 0);
      acc[mt][1] = MFMA32(wf[1], af, acc[mt][1], 0, 0, 0);
    }
    write_actT<false>(bufA, acc, sv, lane, wave);
    BAR_LDS();
  }

  // ---- shared trunk: x2 in place, saved to regs ----
  gemm_acc(bufA, W2w, acc, lane, wave, ones);
  BAR_LDS();
  write_actT<true>(bufA, acc, sv, lane, wave);
  BAR_LDS();

  // ---- branch 1: x31 (in place), then x41 + f51 fused (+ restore x2) ----
  gemm_acc(bufA, W31w, acc, lane, wave, ones);
  BAR_LDS();
  write_actT<false>(bufA, acc, sv, lane, wave);
  BAR_LDS();

  gemm_acc(bufA, W41w, acc, lane, wave, ones);
  BAR_LDS();   // all x31 reads done -> restore may overwrite bufA
  fused_final<true>(acc, sv, w5pk + (size_t)h * (KS17 * 512), s5,
                    ws51 + (size_t)h * BN * 2, bufA, row0, tid, lane, wave, ones);

  // ---- branch 2: x32 (in place, bufA = x2), then x42 + f52 fused ----
  gemm_acc(bufA, W32w, acc, lane, wave, ones);
  BAR_LDS();
  write_actT<false>(bufA, acc, sv, lane, wave);
  BAR_LDS();

  gemm_acc(bufA, W42w, acc, lane, wave, ones);
  fused_final<false>(acc, sv, w5pk + (size_t)(HN + h) * (KS17 * 512), s5,
                     ws52 + (size_t)h * BN * 2, bufA, row0, tid, lane, wave, ones);
}

// ---------------- epilogue: CBF + softmax-weighted head combine ----------------
extern "C" __global__ __launch_bounds__(256)
void abnet_epi(const float* __restrict__ x, const float* __restrict__ wt,
               const float* __restrict__ mean, const float* __restrict__ stdv,
               const float* __restrict__ mlab, const float* __restrict__ slab,
               const float* __restrict__ ws51, const float* __restrict__ ws52,
               float* __restrict__ out)
{
  const int row = blockIdx.x * 256 + threadIdx.x;
  f32x4_t xr = *(const f32x4_t*)(x + (size_t)row * 4);
  float t1  = xr[0] * stdv[0] + mean[0];
  float w1v = xr[1] * stdv[1] + mean[1];
  float t2  = xr[2] * stdv[2] + mean[2];
  float w2v = xr[3] * stdv[3] + mean[3];
  float s1, c1, s2, c2;
  sincosf(t1, &s1, &c1);
  sincosf(t2, &s2, &c2);
  float px = 3.f * c1 + 3.f * c2;                // OBS_X = 0
  float py = 3.f * s1 + 3.f * s2 - 7.f;          // OBS_Y = 7
  float vx = -3.f * s1 * w1v - 3.f * s2 * w2v;
  float vy =  3.f * c1 * w1v + 3.f * c2 * w2v;
  float e_bar  = px * px + py * py - 16.f;       // R^2
  float e_bdot = 2.f * (px * vx + py * vy);
  float e_lf2b = 2.f * vx * vx + 2.f * vy * vy
               + 2.f * px * (-3.f * c1 * w1v * w1v - 3.f * c2 * w2v * w2v)
               + 2.f * py * (-3.f * s1 * w1v * w1v - 3.f * s2 * w2v * w2v);
  float e_g1 = 6.f * (px * s1 - py * c1);
  float e_g2 = 6.f * (px * s2 - py * c2);
  float e_ggi = 1.f / (e_g1 * e_g1 + e_g2 * e_g2);

  float m = wt[0];
  for (int i = 1; i < HN; ++i) m = fmaxf(m, wt[i]);
  float s = 0.f;
  for (int i = 0; i < HN; ++i) s += __expf(wt[i] - m);
  float sm_inv = 1.f / s;
  float ml0 = mlab[0], ml1 = mlab[1];
  float isl0 = 1.f / slab[0], isl1 = 1.f / slab[1];

  float a0r = 4.f / (1.f + __expf(-ws52[(size_t)row * 2 + 0]));   // head 0, col 0
  float accu0 = 0.f, accu1 = 0.f;
  for (int h = 0; h < HN; ++h) {
    float u1 = -ws51[((size_t)h * BN + row) * 2 + 0];
    float u2 = -ws51[((size_t)h * BN + row) * 2 + 1];
    float bi = 4.f / (1.f + __expf(-ws52[((size_t)h * BN + row) * 2 + 1]));
    float hv   = e_lf2b + (a0r + bi) * e_bdot + a0r * bi * e_bar;
    float viol = u1 * e_g1 + u2 * e_g2 - hv;
    float lam  = fmaxf(viol, 0.f) * e_ggi;
    float uu1 = u1 - lam * e_g1;
    float uu2 = u2 - lam * e_g2;
    float whv = __expf(wt[h] - m) * sm_inv;
    accu0 += whv * (uu1 - ml0) * isl0;
    accu1 += whv * (uu2 - ml1) * isl1;
  }
  float2 o; o.x = accu0; o.y = accu1;
  *(float2*)(out + (size_t)row * 2) = o;
}

// ---------------- launch ----------------
extern "C" void kernel_launch(void* const* d_in, const int* in_sizes, int n_in,
                              void* d_out, int out_size, void* d_ws, size_t ws_size,
                              hipStream_t stream)
{
  const float* x    = (const float*)d_in[0];
  const float* wt   = (const float*)d_in[2];
  const float* mean = (const float*)d_in[3];
  const float* stdv = (const float*)d_in[4];
  const float* mlab = (const float*)d_in[5];
  const float* slab = (const float*)d_in[6];
  const float* W1   = (const float*)d_in[7];
  const float* b1   = (const float*)d_in[8];
  WPtrs wp;
  wp.w[0] = (const float*)d_in[9];   // W2
  wp.w[1] = (const float*)d_in[11];  // W31
  wp.w[2] = (const float*)d_in[13];  // W32
  wp.w[3] = (const float*)d_in[15];  // W41
  wp.w[4] = (const float*)d_in[17];  // W42
  wp.b[0] = (const float*)d_in[10];  // b2
  wp.b[1] = (const float*)d_in[12];  // b31
  wp.b[2] = (const float*)d_in[14];  // b32
  wp.b[3] = (const float*)d_in[16];  // b41
  wp.b[4] = (const float*)d_in[18];  // b42
  const float* W51 = (const float*)d_in[19];
  const float* b51 = (const float*)d_in[20];
  const float* W52 = (const float*)d_in[21];
  const float* b52 = (const float*)d_in[22];

  char* wsb = (char*)d_ws;
  unsigned short* wpk  = (unsigned short*)wsb;                       // 6,963,200 B
  unsigned short* w5pk = (unsigned short*)(wsb + 6963200);           //   348,160 B
  unsigned short* w1pk = (unsigned short*)(wsb + 7311360);           //    81,920 B
  float* ws51 = (float*)(wsb + 7393280);                             // 2,621,440 B
  float* ws52 = (float*)(wsb + 10014720);                            // 2,621,440 B

  hipLaunchKernelGGL(pack_big, dim3(1700), dim3(256), 0, stream, wp, wpk);
  hipLaunchKernelGGL(pack_w5,  dim3(85),   dim3(256), 0, stream, W51, W52, b51, b52, w5pk);
  hipLaunchKernelGGL(pack_w1,  dim3(20),   dim3(256), 0, stream, W1, b1, w1pk);

  (void)hipFuncSetAttribute(reinterpret_cast<const void*>(abnet_main),
                            hipFuncAttributeMaxDynamicSharedMemorySize, SMEM_BYTES);
  hipLaunchKernelGGL(abnet_main, dim3(512 * HN), dim3(256), SMEM_BYTES, stream,
                     x, wpk, w5pk, w1pk, ws51, ws52);
  hipLaunchKernelGGL(abnet_epi, dim3(BN / 256), dim3(256), 0, stream,
                     x, wt, mean, stdv, mlab, slab, ws51, ws52, (float*)d_out);
}